// Round 2
// baseline (848.436 us; speedup 1.0000x reference)
//
#include <hip/hip_runtime.h>
#include <hip/hip_bf16.h>
#include <math.h>

#define N_ROWS 16384
#define DIM    256
#define NE     8192
#define QMARGIN 21   // ceil(eps/step)+1, step=2^-17, eps~1.5e-4

// ---- out layout (float indices) ----
// loss @0 | z_q_st @1 (4194304) | perp @4194305 | one_hot @4194306 (134217728)
// indices @138412034 (16384)
//
// ---- scratch INSIDE one_hot region (rows 0..962), 16B-aligned ----
// SOFF = 4194308
// zf    @ SOFF+0         (4194304 f32)   z as (N,D)
// zfb   @ SOFF+4194304   (4194304 bf16)  fragment-order bf16 z
// ewb   @ SOFF+6291456   (2097152 bf16)  fragment-order bf16 codebook
// part  @ SOFF+7340032   (524288 i32)    per row: 8 byc x 2 wn x (k1,k2)
// lprt  @ SOFF+7864320   (16384 f32)
// ghist @ 12075012       (8192 i32)      ends @ 12083204 == Z4_BASE
//
// one_hot production:
//   rows 963..16383 bulk ([12083204,138412032) float4s): NT-zeroed in k_score,
//     bursted 16/thread at kt==0 (7 of 8 barriers drain no stores).
//   rows 0..962 (scratch lives here until k_scalars): idx-aware zero+ones in
//     k_zq_out, distributed over all 4096 blocks.
//   ones for rows>=963: k_zq_out scattered stores (region pre-zeroed by k_score).
//   boundary words (row962 cols 8190/8191, row963 cols 0/1 = ghist tail,
//     row16383 cols 8190/8191): single thread in k_zq_out.
#define SOFF 4194308
#define GHOFF 12075012ULL
#define Z4_BASE 12083204ULL         // 16B-aligned float4 base (rows>=963 bulk)
#define N4_TOTAL 31582207ULL        // float4 count in bulk region
#define C4_PER_BLK 30843ULL         // ceil per 1024 k_score blocks
#define ZQ4_COUNT 1972223ULL        // float4s in rows 0..962 region (rel [2,7888894))
#define ZQ4_PER_BLK 482             // ceil(ZQ4_COUNT/4096)

typedef __bf16 bf16x8 __attribute__((ext_vector_type(8)));
typedef float  f32x4  __attribute__((ext_vector_type(4)));
typedef float  vf4    __attribute__((ext_vector_type(4)));

__device__ __forceinline__ void gload_lds16(const __bf16* g, __bf16* l) {
  __builtin_amdgcn_global_load_lds(
      (const __attribute__((address_space(1))) unsigned int*)g,
      (__attribute__((address_space(3))) unsigned int*)l, 16, 0, 0);
}

// ---------- kernel 1: z transpose -> zf fp32 + zfb fragment bf16; fused
// codebook cvt (fid<1024) and ghist zero (fid 1024..1055) ----------
__global__ void k_prep(const float* __restrict__ z, const float* __restrict__ ew,
                       float* __restrict__ zf, __bf16* __restrict__ zfb,
                       __bf16* __restrict__ ewb, int* __restrict__ ghist) {
  __shared__ float tile[32][33];
  int ct = blockIdx.x, ht = blockIdx.y, b = blockIdx.z;
  int tx = threadIdx.x & 31, ty = threadIdx.x >> 5;
  int c0 = ct * 32, hw0 = ht * 32;
  const size_t zb = (size_t)b * 256 * 1024;
#pragma unroll
  for (int p = 0; p < 4; ++p) {
    int c = p * 8 + ty;
    tile[c][tx] = z[zb + (size_t)(c0 + c) * 1024 + hw0 + tx];
  }
  __syncthreads();
#pragma unroll
  for (int p = 0; p < 4; ++p) {
    int r = p * 8 + ty;
    zf[(size_t)(b * 1024 + hw0 + r) * DIM + c0 + tx] = tile[tx][r];
  }
  if (threadIdx.x < 128) {
    int r = threadIdx.x >> 2, kc = threadIdx.x & 3;
    int row = b * 1024 + hw0 + r;
    bf16x8 v;
#pragma unroll
    for (int j = 0; j < 8; ++j) v[j] = (__bf16)tile[kc * 8 + j][r];
    int tn = row >> 7, g = (row >> 4) & 7, m15 = row & 15, kt = c0 >> 5;
    *(bf16x8*)(zfb + (size_t)tn * 32768 + kt * 4096 + g * 512 + (kc * 16 + m15) * 8) = v;
  }
  // fused k_cvt_e + ghist zero
  const int fid = blockIdx.x + 8 * blockIdx.y + 256 * blockIdx.z;
  if (fid < 1024) {
    int gid = fid * 256 + threadIdx.x;  // 0..262143
    int r = gid >> 5, kc8 = gid & 31;
    const float* s = ew + (size_t)r * DIM + kc8 * 8;
    float4 v0 = *(const float4*)s, v1 = *(const float4*)(s + 4);
    bf16x8 v = {(__bf16)v0.x, (__bf16)v0.y, (__bf16)v0.z, (__bf16)v0.w,
                (__bf16)v1.x, (__bf16)v1.y, (__bf16)v1.z, (__bf16)v1.w};
    int t = r >> 7, g = (r >> 4) & 7, m15 = r & 15, kt = kc8 >> 2, kc = kc8 & 3;
    *(bf16x8*)(ewb + (size_t)t * 32768 + kt * 4096 + g * 512 + (kc * 16 + m15) * 8) = v;
  } else if (fid < 1056) {
    ghist[(fid - 1024) * 256 + threadIdx.x] = 0;
  }
}

// ---------- kernel 2: persistent-A MFMA scores, running reg top-2, 1 shfl merge ----------
// + bursted NT zero-fill of one_hot rows>=963 bulk at kt==0 only
__global__ __launch_bounds__(256, 2) void k_score(const __bf16* __restrict__ zfb,
                                                  const __bf16* __restrict__ ewb,
                                                  int2* __restrict__ part2,
                                                  float* __restrict__ oz) {
  __shared__ __align__(16) __bf16 Afull[32768];   // 64 KB: full 128x256 A tile
  __shared__ __align__(16) __bf16 Bs[2][4096];    // 2 x 8 KB B tiles
  const int tid = threadIdx.x;
  const int lane = tid & 63, wave = tid >> 6;
  const int wm = wave >> 1, wn = wave & 1;
  const int quad = lane >> 4, l15 = lane & 15;
  const int bx = blockIdx.x, byc = blockIdx.y;
  const int bid = byc * 128 + bx;              // 0..1023
  const __bf16* Ag = zfb + (size_t)bx * 32768;
  const __bf16* Bg = ewb + (size_t)byc * 262144;
  const size_t blk4 = (size_t)bid * C4_PER_BLK;
  f32x4* zdst = (f32x4*)(oz + Z4_BASE);
  const f32x4 zero4 = {0.f, 0.f, 0.f, 0.f};

  // stage A once (16 KB per wave)
  {
    const int base = wave * 8192;
#pragma unroll
    for (int i = 0; i < 16; ++i)
      gload_lds16(Ag + base + i * 512 + lane * 8, Afull + base + i * 512);
  }
  // prefetch B for iter 0
  {
    const int boff = wave * 1024;
    gload_lds16(Bg + boff + lane * 8, Bs[0] + boff);
    gload_lds16(Bg + boff + 512 + lane * 8, Bs[0] + boff + 512);
  }

  f32x4 acc[4][4];
#pragma unroll
  for (int i = 0; i < 4; ++i)
#pragma unroll
    for (int j = 0; j < 4; ++j) acc[i][j] = (f32x4){0.f, 0.f, 0.f, 0.f};
  int r1[16], r2[16];
#pragma unroll
  for (int i = 0; i < 16; ++i) { r1[i] = 0x7fffffff; r2[i] = 0x7fffffff; }

  for (int it = 0; it < 64; ++it) {
    const int bt = it >> 3, kt = it & 7, buf = it & 1;
    __syncthreads();
    if (it < 63) {
      const int nx = it + 1;
      const __bf16* src = Bg + (nx >> 3) * 32768 + (nx & 7) * 4096 + wave * 1024;
      gload_lds16(src + lane * 8, Bs[buf ^ 1] + wave * 1024);
      gload_lds16(src + 512 + lane * 8, Bs[buf ^ 1] + wave * 1024 + 512);
    }
    // bursted zero-fill: 16 x float4 NT per thread, once per 8 iterations,
    // issued right after the barrier so 7/8 barriers drain no stores.
    if (kt == 0) {
      const int burst = it >> 3;  // 0..7
#pragma unroll
      for (int s = 0; s < 16; ++s) {
        size_t slot = (size_t)(burst * 16 + s) * 256 + tid;
        if (slot < C4_PER_BLK) {
          size_t g4 = blk4 + slot;
          if (g4 < N4_TOTAL) __builtin_nontemporal_store(zero4, zdst + g4);
        }
      }
    }
    bf16x8 af[4], bfr[4];
#pragma unroll
    for (int mi = 0; mi < 4; ++mi)
      af[mi] = *(const bf16x8*)(Afull + kt * 4096 + (wm * 4 + mi) * 512 + lane * 8);
#pragma unroll
    for (int ni = 0; ni < 4; ++ni)
      bfr[ni] = *(const bf16x8*)(Bs[buf] + (wn * 4 + ni) * 512 + lane * 8);
#pragma unroll
    for (int mi = 0; mi < 4; ++mi)
#pragma unroll
      for (int ni = 0; ni < 4; ++ni)
        acc[mi][ni] = __builtin_amdgcn_mfma_f32_16x16x32_bf16(af[mi], bfr[ni],
                                                              acc[mi][ni], 0, 0, 0);
    if (kt == 7) {
      const int colb = byc * 1024 + bt * 128 + wn * 64;
#pragma unroll
      for (int mi = 0; mi < 4; ++mi) {
#pragma unroll
        for (int rg = 0; rg < 4; ++rg) {
          const int idx = mi * 4 + rg;
          float s0 = -2.f * acc[mi][0][rg], s1 = -2.f * acc[mi][1][rg];
          float s2 = -2.f * acc[mi][2][rg], s3 = -2.f * acc[mi][3][rg];
          int q0 = min(max((int)((s0 + 1.0f) * 131072.0f), 0), 262143);
          int q1 = min(max((int)((s1 + 1.0f) * 131072.0f), 0), 262143);
          int q2 = min(max((int)((s2 + 1.0f) * 131072.0f), 0), 262143);
          int q3 = min(max((int)((s3 + 1.0f) * 131072.0f), 0), 262143);
          int k0 = (q0 << 13) | (colb + l15);
          int k1 = (q1 << 13) | (colb + 16 + l15);
          int k2 = (q2 << 13) | (colb + 32 + l15);
          int k3 = (q3 << 13) | (colb + 48 + l15);
          int a = min(k0, k1), bb = max(k0, k1);
          int c = min(k2, k3), dd = max(k2, k3);
          int t1 = min(a, c);
          int t2 = min(max(a, c), min(bb, dd));
          int n1 = min(r1[idx], t1);
          int n2 = min(max(r1[idx], t1), min(r2[idx], t2));
          r1[idx] = n1; r2[idx] = n2;
        }
      }
#pragma unroll
      for (int i = 0; i < 4; ++i)
#pragma unroll
        for (int j = 0; j < 4; ++j) acc[i][j] = (f32x4){0.f, 0.f, 0.f, 0.f};
    }
  }

  // single final 16-lane lex merge + store
#pragma unroll
  for (int mi = 0; mi < 4; ++mi) {
#pragma unroll
    for (int rg = 0; rg < 4; ++rg) {
      const int idx = mi * 4 + rg;
      int k1 = r1[idx], k2 = r2[idx];
#pragma unroll
      for (int d = 1; d < 16; d <<= 1) {
        int o1 = __shfl_xor(k1, d), o2 = __shfl_xor(k2, d);
        k2 = min(max(k1, o1), min(k2, o2));
        k1 = min(k1, o1);
      }
      if (l15 == 0) {
        int row = bx * 128 + wm * 64 + mi * 16 + quad * 4 + rg;
        int2 v; v.x = k1; v.y = k2;
        part2[row * 16 + byc * 2 + wn] = v;
      }
    }
  }
}

// ---------- numpy-pairwise-exact sum of squares over 128 ----------
__device__ __forceinline__ float np_sumsq_128(const float* __restrict__ p) {
  float r[8];
#pragma unroll
  for (int j = 0; j < 8; ++j) r[j] = __fmul_rn(p[j], p[j]);
  for (int i = 8; i < 128; i += 8) {
#pragma unroll
    for (int j = 0; j < 8; ++j) r[j] = __fadd_rn(r[j], __fmul_rn(p[i + j], p[i + j]));
  }
  return __fadd_rn(__fadd_rn(__fadd_rn(r[0], r[1]), __fadd_rn(r[2], r[3])),
                   __fadd_rn(__fadd_rn(r[4], r[5]), __fadd_rn(r[6], r[7])));
}

// ---------- kernel 3: wave-per-row candidate filter + exact fp32 rescore ----------
__global__ __launch_bounds__(256) void k_pick(const int2* __restrict__ part2,
                                              const float* __restrict__ zf,
                                              const float* __restrict__ ew,
                                              float* __restrict__ idxF,
                                              float* __restrict__ losspart,
                                              int* __restrict__ ghist) {
  __shared__ int cand[4][40];
  __shared__ int cnts[4];
  const int t = threadIdx.x, lane = t & 63, wv = t >> 6;
  const int row = blockIdx.x * 4 + wv;
  if (lane == 0) cnts[wv] = 0;
  int2 pv;
  if (lane < 16) pv = part2[row * 16 + lane];
  else { pv.x = 0x7fffffff; pv.y = 0x7fffffff; }
  int kmin = pv.x;
#pragma unroll
  for (int d = 1; d < 64; d <<= 1) kmin = min(kmin, __shfl_xor(kmin, d));
  const int qthr = min((kmin >> 13) + QMARGIN, 262143);
  const int kthr = (qthr << 13) | 8191;
  __syncthreads();
  if (lane < 16) {
    if (pv.x <= kthr) { int p = atomicAdd(&cnts[wv], 1); cand[wv][p] = pv.x & 8191; }
    if (pv.y <= kthr) { int p = atomicAdd(&cnts[wv], 1); cand[wv][p] = pv.y & 8191; }
  }
  __syncthreads();
  const int cnt = cnts[wv];
  const float* zr = zf + (size_t)row * DIM;
  float bd = INFINITY; int bj = 0x7fffffff;
  if (lane < cnt) {
    int j = cand[wv][lane];
    const float* e = ew + (size_t)j * DIM;
    float acc = 0.f;
    for (int k = 0; k < DIM; k += 4) {   // float4 loads, same sequential fma order
      float4 e4 = *(const float4*)(e + k);
      float4 z4 = *(const float4*)(zr + k);
      acc = __builtin_fmaf(z4.x, e4.x, acc);
      acc = __builtin_fmaf(z4.y, e4.y, acc);
      acc = __builtin_fmaf(z4.z, e4.z, acc);
      acc = __builtin_fmaf(z4.w, e4.w, acc);
    }
    float esq = __fadd_rn(np_sumsq_128(e), np_sumsq_128(e + 128));
    float zsq = __fadd_rn(np_sumsq_128(zr), np_sumsq_128(zr + 128));
    bd = __fsub_rn(__fadd_rn(zsq, esq), __fmul_rn(2.0f, acc));
    bj = j;
  }
#pragma unroll
  for (int d = 1; d < 64; d <<= 1) {
    float od = __shfl_xor(bd, d); int oj = __shfl_xor(bj, d);
    if (od < bd || (od == bd && oj < bj)) { bd = od; bj = oj; }
  }
  // loss partial
  int c = lane * 4;
  float4 e4 = *reinterpret_cast<const float4*>(ew + (size_t)bj * DIM + c);
  float4 z4 = *reinterpret_cast<const float4*>(zr + c);
  float t0 = __fsub_rn(e4.x, z4.x), t1 = __fsub_rn(e4.y, z4.y);
  float t2 = __fsub_rn(e4.z, z4.z), t3 = __fsub_rn(e4.w, z4.w);
  float s = __fadd_rn(__fadd_rn(__fmul_rn(t0, t0), __fmul_rn(t1, t1)),
                      __fadd_rn(__fmul_rn(t2, t2), __fmul_rn(t3, t3)));
#pragma unroll
  for (int d = 1; d < 64; d <<= 1) s += __shfl_xor(s, d);
  if (lane == 0) {
    idxF[row] = (float)bj;
    losspart[row] = s;
    atomicAdd(&ghist[bj], 1);   // device-scope histogram, replaces k_scalars pass
  }
}

// ---------- kernel 4: loss + perplexity (reads prebuilt ghist) ----------
__global__ __launch_bounds__(256) void k_scalars(const int* __restrict__ ghist,
                                                 const float* __restrict__ losspart,
                                                 float* __restrict__ out) {
  __shared__ float red[256];
  int t = threadIdx.x;
  float ls = 0.f;
  for (int i = t; i < N_ROWS; i += 256) ls += losspart[i];
  float es = 0.f;
  for (int i = t; i < NE; i += 256) {
    float p = (float)ghist[i] * (1.0f / 16384.0f);
    es += p * logf(p + 1e-10f);
  }
  red[t] = es; __syncthreads();
  for (int w = 128; w > 0; w >>= 1) { if (t < w) red[t] += red[t + w]; __syncthreads(); }
  float esum = red[0]; __syncthreads();
  red[t] = ls; __syncthreads();
  for (int w = 128; w > 0; w >>= 1) { if (t < w) red[t] += red[t + w]; __syncthreads(); }
  if (t == 0) {
    out[4194305] = expf(-esum);
    float m = red[0] * (1.0f / 4194304.0f);
    out[0] = __fadd_rn(m, __fmul_rn(0.25f, m));
  }
}

// ---------- kernel 5 (LAST): z_q_st + one_hot finish ----------
__global__ void k_zq_out(const float* __restrict__ z, const float* __restrict__ ew,
                         const float* __restrict__ idxF, float* __restrict__ out) {
  __shared__ float tileE[32][33];
  __shared__ int sidx[32];
  int ct = blockIdx.x, ht = blockIdx.y, b = blockIdx.z;
  int tx = threadIdx.x & 31, ty = threadIdx.x >> 5;
  int c0 = ct * 32, hw0 = ht * 32;
  if (threadIdx.x < 32) sidx[threadIdx.x] = (int)idxF[b * 1024 + hw0 + threadIdx.x];
  __syncthreads();
#pragma unroll
  for (int p = 0; p < 4; ++p) {
    int r = p * 8 + ty;
    tileE[tx][r] = ew[(size_t)sidx[r] * DIM + c0 + tx];
  }
  __syncthreads();
  float* outq = out + 1;
#pragma unroll
  for (int p = 0; p < 4; ++p) {
    int cl = p * 8 + ty;
    size_t gi = (size_t)(b * 256 + c0 + cl) * 1024 + hw0 + tx;
    float zv = z[gi];
    outq[gi] = __fadd_rn(zv, __fsub_rn(tileE[cl][tx], zv));
  }

  // ---- fused one_hot finish (all scratch dead by now) ----
  const int fid = blockIdx.x + 8 * blockIdx.y + 256 * blockIdx.z;  // 0..4095
  float* oh = out + 4194306;
  // (a) idx-aware zero/ones of rows 0..962, float4 region rel [2, 7888894)
  {
    f32x4* dst4 = (f32x4*)(out + 4194308);
#pragma unroll
    for (int p = 0; p < 2; ++p) {
      int slot = p * 256 + (int)threadIdx.x;
      size_t g4 = (size_t)fid * ZQ4_PER_BLK + slot;
      if (slot < ZQ4_PER_BLK && g4 < ZQ4_COUNT) {
        size_t rel = g4 * 4 + 2;
        int ra = (int)(rel >> 13), rb = (int)((rel + 3) >> 13);
        int ia = (int)idxF[ra];
        int ib = (ra == rb) ? ia : (int)idxF[rb];
        f32x4 v;
#pragma unroll
        for (int j = 0; j < 4; ++j) {
          size_t rj = rel + j;
          int rowj = (int)(rj >> 13), colj = (int)(rj & 8191);
          int idxj = (rowj == ra) ? ia : ib;
          v[j] = (colj == idxj) ? 1.f : 0.f;
        }
        __builtin_nontemporal_store(v, dst4 + g4);
      }
    }
  }
  // (b) scattered ones for rows >= 963 (bulk pre-zeroed by k_score)
  if (threadIdx.x < 4) {
    int r = fid * 4 + (int)threadIdx.x;
    if (r >= 963 && r < N_ROWS) {
      int idx = (int)idxF[r];
      oh[(size_t)r * NE + idx] = 1.0f;
    }
  }
  // (c) boundary words: row0 cols0/1, row962 cols 8190/8191,
  //     row963 cols0/1 (ghist tail restore), row16383 cols 8190/8191
  if (fid == 0 && threadIdx.x == 4) {
    int i0 = (int)idxF[0];
    oh[0] = (i0 == 0) ? 1.f : 0.f;
    oh[1] = (i0 == 1) ? 1.f : 0.f;
    int i962 = (int)idxF[962];
    oh[(size_t)962 * NE + 8190] = (i962 == 8190) ? 1.f : 0.f;
    oh[(size_t)962 * NE + 8191] = (i962 == 8191) ? 1.f : 0.f;
    int i963 = (int)idxF[963];
    oh[(size_t)963 * NE + 0] = (i963 == 0) ? 1.f : 0.f;
    oh[(size_t)963 * NE + 1] = (i963 == 1) ? 1.f : 0.f;
    int il = (int)idxF[16383];
    oh[(size_t)16383 * NE + 8190] = (il == 8190) ? 1.f : 0.f;
    oh[(size_t)16383 * NE + 8191] = (il == 8191) ? 1.f : 0.f;
  }
}

extern "C" void kernel_launch(void* const* d_in, const int* in_sizes, int n_in,
                              void* d_out, int out_size, void* d_ws, size_t ws_size,
                              hipStream_t stream) {
  const float* z  = (const float*)d_in[0];
  const float* ew = (const float*)d_in[1];
  float* out = (float*)d_out;
  float*  zf    = out + SOFF;
  __bf16* zfb   = (__bf16*)(out + SOFF + 4194304);
  __bf16* ewb   = (__bf16*)(out + SOFF + 6291456);
  int2*   part2 = (int2*)(out + SOFF + 7340032);
  float*  lprt  = out + SOFF + 7864320;
  int*    ghist = (int*)(out + GHOFF);
  float*  idxF  = out + 138412034;

  k_prep<<<dim3(8, 32, 16), 256, 0, stream>>>(z, ew, zf, zfb, ewb, ghist);
  k_score<<<dim3(128, 8), 256, 0, stream>>>(zfb, ewb, part2, out);
  k_pick<<<dim3(4096), 256, 0, stream>>>(part2, zf, ew, idxF, lprt, ghist);
  k_scalars<<<1, 256, 0, stream>>>(ghist, lprt, out);
  k_zq_out<<<dim3(8, 32, 16), 256, 0, stream>>>(z, ew, idxF, out);
}

// Round 3
// 821.102 us; speedup vs baseline: 1.0333x; 1.0333x over previous
//
#include <hip/hip_runtime.h>
#include <hip/hip_bf16.h>
#include <math.h>

#define N_ROWS 16384
#define DIM    256
#define NE     8192
#define QMARGIN 21   // ceil(eps/step)+1, step=2^-17, eps~1.5e-4

// ---- out layout (float indices) ----
// loss @0 | z_q_st @1 (4194304) | perp @4194305 | one_hot @4194306 (134217728)
// indices @138412034 (16384)
//
// ---- scratch INSIDE one_hot region (rows 0..962), 16B-aligned ----
// SOFF = 4194308
// zf    @ SOFF+0         (4194304 f32)   z as (N,D)
// zfb   @ SOFF+4194304   (4194304 bf16)  fragment-order bf16 z
// ewb   @ SOFF+6291456   (2097152 bf16)  fragment-order bf16 codebook
// part  @ SOFF+7340032   (524288 i32)    per row: 8 byc x 2 wn x (k1,k2)
// lprt  @ SOFF+7864320   (16384 f32)
// ghist @ 12075012       (8192 i32)      ends @ 12083204 == Z4_BASE
//
// one_hot production:
//   rows 963..16383 bulk ([12083204,138412032) float4s): NT-zeroed in k_score,
//     SPREAD 2 float4/thread/iter (round-1 pattern: each barrier drains <=2
//     store-acks that had a full MFMA iteration to retire; the round-2 burst
//     variant serialized ~10us drains and regressed).
//   rows 0..962 (scratch lives here until k_scalars): idx-aware zero+ones in
//     k_zq_out, distributed over all 4096 blocks.
//   ones for rows>=963: k_zq_out scattered stores (region pre-zeroed by k_score).
//   boundary words (row0 cols0/1, row962 cols 8190/8191, row963 cols 0/1 =
//     ghist tail, row16383 cols 8190/8191): single thread in k_zq_out.
#define SOFF 4194308
#define GHOFF 12075012ULL
#define Z4_BASE 12083204ULL         // 16B-aligned float4 base (rows>=963 bulk)
#define N4_TOTAL 31582207ULL        // float4 count in bulk region
#define C4_PER_BLK 30843ULL         // ceil per 1024 k_score blocks
#define ZQ4_COUNT 1972223ULL        // float4s in rows 0..962 region (rel [2,7888894))
#define ZQ4_PER_BLK 482             // ceil(ZQ4_COUNT/4096)

typedef __bf16 bf16x8 __attribute__((ext_vector_type(8)));
typedef float  f32x4  __attribute__((ext_vector_type(4)));
typedef float  vf4    __attribute__((ext_vector_type(4)));

__device__ __forceinline__ void gload_lds16(const __bf16* g, __bf16* l) {
  __builtin_amdgcn_global_load_lds(
      (const __attribute__((address_space(1))) unsigned int*)g,
      (__attribute__((address_space(3))) unsigned int*)l, 16, 0, 0);
}

// ---------- kernel 1: z transpose -> zf fp32 + zfb fragment bf16; fused
// codebook cvt (fid<1024) and ghist zero (fid 1024..1055) ----------
__global__ void k_prep(const float* __restrict__ z, const float* __restrict__ ew,
                       float* __restrict__ zf, __bf16* __restrict__ zfb,
                       __bf16* __restrict__ ewb, int* __restrict__ ghist) {
  __shared__ float tile[32][33];
  int ct = blockIdx.x, ht = blockIdx.y, b = blockIdx.z;
  int tx = threadIdx.x & 31, ty = threadIdx.x >> 5;
  int c0 = ct * 32, hw0 = ht * 32;
  const size_t zb = (size_t)b * 256 * 1024;
#pragma unroll
  for (int p = 0; p < 4; ++p) {
    int c = p * 8 + ty;
    tile[c][tx] = z[zb + (size_t)(c0 + c) * 1024 + hw0 + tx];
  }
  __syncthreads();
#pragma unroll
  for (int p = 0; p < 4; ++p) {
    int r = p * 8 + ty;
    zf[(size_t)(b * 1024 + hw0 + r) * DIM + c0 + tx] = tile[tx][r];
  }
  if (threadIdx.x < 128) {
    int r = threadIdx.x >> 2, kc = threadIdx.x & 3;
    int row = b * 1024 + hw0 + r;
    bf16x8 v;
#pragma unroll
    for (int j = 0; j < 8; ++j) v[j] = (__bf16)tile[kc * 8 + j][r];
    int tn = row >> 7, g = (row >> 4) & 7, m15 = row & 15, kt = c0 >> 5;
    *(bf16x8*)(zfb + (size_t)tn * 32768 + kt * 4096 + g * 512 + (kc * 16 + m15) * 8) = v;
  }
  // fused k_cvt_e + ghist zero
  const int fid = blockIdx.x + 8 * blockIdx.y + 256 * blockIdx.z;
  if (fid < 1024) {
    int gid = fid * 256 + threadIdx.x;  // 0..262143
    int r = gid >> 5, kc8 = gid & 31;
    const float* s = ew + (size_t)r * DIM + kc8 * 8;
    float4 v0 = *(const float4*)s, v1 = *(const float4*)(s + 4);
    bf16x8 v = {(__bf16)v0.x, (__bf16)v0.y, (__bf16)v0.z, (__bf16)v0.w,
                (__bf16)v1.x, (__bf16)v1.y, (__bf16)v1.z, (__bf16)v1.w};
    int t = r >> 7, g = (r >> 4) & 7, m15 = r & 15, kt = kc8 >> 2, kc = kc8 & 3;
    *(bf16x8*)(ewb + (size_t)t * 32768 + kt * 4096 + g * 512 + (kc * 16 + m15) * 8) = v;
  } else if (fid < 1056) {
    ghist[(fid - 1024) * 256 + threadIdx.x] = 0;
  }
}

// ---------- kernel 2: persistent-A MFMA scores, running reg top-2, 1 shfl merge ----------
// + interleaved NT zero-fill of one_hot rows>=963 bulk (2 float4/thread/iter)
__global__ __launch_bounds__(256, 2) void k_score(const __bf16* __restrict__ zfb,
                                                  const __bf16* __restrict__ ewb,
                                                  int2* __restrict__ part2,
                                                  float* __restrict__ oz) {
  __shared__ __align__(16) __bf16 Afull[32768];   // 64 KB: full 128x256 A tile
  __shared__ __align__(16) __bf16 Bs[2][4096];    // 2 x 8 KB B tiles
  const int tid = threadIdx.x;
  const int lane = tid & 63, wave = tid >> 6;
  const int wm = wave >> 1, wn = wave & 1;
  const int quad = lane >> 4, l15 = lane & 15;
  const int bx = blockIdx.x, byc = blockIdx.y;
  const int bid = byc * 128 + bx;              // 0..1023
  const __bf16* Ag = zfb + (size_t)bx * 32768;
  const __bf16* Bg = ewb + (size_t)byc * 262144;
  const size_t blk4 = (size_t)bid * C4_PER_BLK;
  f32x4* zdst = (f32x4*)(oz + Z4_BASE);
  const f32x4 zero4 = {0.f, 0.f, 0.f, 0.f};

  // stage A once (16 KB per wave)
  {
    const int base = wave * 8192;
#pragma unroll
    for (int i = 0; i < 16; ++i)
      gload_lds16(Ag + base + i * 512 + lane * 8, Afull + base + i * 512);
  }
  // prefetch B for iter 0
  {
    const int boff = wave * 1024;
    gload_lds16(Bg + boff + lane * 8, Bs[0] + boff);
    gload_lds16(Bg + boff + 512 + lane * 8, Bs[0] + boff + 512);
  }

  f32x4 acc[4][4];
#pragma unroll
  for (int i = 0; i < 4; ++i)
#pragma unroll
    for (int j = 0; j < 4; ++j) acc[i][j] = (f32x4){0.f, 0.f, 0.f, 0.f};
  int r1[16], r2[16];
#pragma unroll
  for (int i = 0; i < 16; ++i) { r1[i] = 0x7fffffff; r2[i] = 0x7fffffff; }

  for (int it = 0; it < 64; ++it) {
    const int bt = it >> 3, kt = it & 7, buf = it & 1;
    __syncthreads();
    if (it < 63) {
      const int nx = it + 1;
      const __bf16* src = Bg + (nx >> 3) * 32768 + (nx & 7) * 4096 + wave * 1024;
      gload_lds16(src + lane * 8, Bs[buf ^ 1] + wave * 1024);
      gload_lds16(src + 512 + lane * 8, Bs[buf ^ 1] + wave * 1024 + 512);
    }
    // interleaved zero-fill: 2 x float4 NT stores per thread per iteration,
    // per-block contiguous chunk, issued right after prefetch so each store
    // has a full MFMA iteration to retire before the next barrier's drain.
    if (it <= 60) {
#pragma unroll
      for (int s = 0; s < 2; ++s) {
        size_t slot = (size_t)(it * 2 + s) * 256 + tid;
        if (slot < C4_PER_BLK) {
          size_t g4 = blk4 + slot;
          if (g4 < N4_TOTAL) __builtin_nontemporal_store(zero4, zdst + g4);
        }
      }
    }
    bf16x8 af[4], bfr[4];
#pragma unroll
    for (int mi = 0; mi < 4; ++mi)
      af[mi] = *(const bf16x8*)(Afull + kt * 4096 + (wm * 4 + mi) * 512 + lane * 8);
#pragma unroll
    for (int ni = 0; ni < 4; ++ni)
      bfr[ni] = *(const bf16x8*)(Bs[buf] + (wn * 4 + ni) * 512 + lane * 8);
#pragma unroll
    for (int mi = 0; mi < 4; ++mi)
#pragma unroll
      for (int ni = 0; ni < 4; ++ni)
        acc[mi][ni] = __builtin_amdgcn_mfma_f32_16x16x32_bf16(af[mi], bfr[ni],
                                                              acc[mi][ni], 0, 0, 0);
    if (kt == 7) {
      const int colb = byc * 1024 + bt * 128 + wn * 64;
#pragma unroll
      for (int mi = 0; mi < 4; ++mi) {
#pragma unroll
        for (int rg = 0; rg < 4; ++rg) {
          const int idx = mi * 4 + rg;
          float s0 = -2.f * acc[mi][0][rg], s1 = -2.f * acc[mi][1][rg];
          float s2 = -2.f * acc[mi][2][rg], s3 = -2.f * acc[mi][3][rg];
          int q0 = min(max((int)((s0 + 1.0f) * 131072.0f), 0), 262143);
          int q1 = min(max((int)((s1 + 1.0f) * 131072.0f), 0), 262143);
          int q2 = min(max((int)((s2 + 1.0f) * 131072.0f), 0), 262143);
          int q3 = min(max((int)((s3 + 1.0f) * 131072.0f), 0), 262143);
          int k0 = (q0 << 13) | (colb + l15);
          int k1 = (q1 << 13) | (colb + 16 + l15);
          int k2 = (q2 << 13) | (colb + 32 + l15);
          int k3 = (q3 << 13) | (colb + 48 + l15);
          int a = min(k0, k1), bb = max(k0, k1);
          int c = min(k2, k3), dd = max(k2, k3);
          int t1 = min(a, c);
          int t2 = min(max(a, c), min(bb, dd));
          int n1 = min(r1[idx], t1);
          int n2 = min(max(r1[idx], t1), min(r2[idx], t2));
          r1[idx] = n1; r2[idx] = n2;
        }
      }
#pragma unroll
      for (int i = 0; i < 4; ++i)
#pragma unroll
        for (int j = 0; j < 4; ++j) acc[i][j] = (f32x4){0.f, 0.f, 0.f, 0.f};
    }
  }

  // single final 16-lane lex merge + store
#pragma unroll
  for (int mi = 0; mi < 4; ++mi) {
#pragma unroll
    for (int rg = 0; rg < 4; ++rg) {
      const int idx = mi * 4 + rg;
      int k1 = r1[idx], k2 = r2[idx];
#pragma unroll
      for (int d = 1; d < 16; d <<= 1) {
        int o1 = __shfl_xor(k1, d), o2 = __shfl_xor(k2, d);
        k2 = min(max(k1, o1), min(k2, o2));
        k1 = min(k1, o1);
      }
      if (l15 == 0) {
        int row = bx * 128 + wm * 64 + mi * 16 + quad * 4 + rg;
        int2 v; v.x = k1; v.y = k2;
        part2[row * 16 + byc * 2 + wn] = v;
      }
    }
  }
}

// ---------- numpy-pairwise-exact sum of squares over 128 ----------
__device__ __forceinline__ float np_sumsq_128(const float* __restrict__ p) {
  float r[8];
#pragma unroll
  for (int j = 0; j < 8; ++j) r[j] = __fmul_rn(p[j], p[j]);
  for (int i = 8; i < 128; i += 8) {
#pragma unroll
    for (int j = 0; j < 8; ++j) r[j] = __fadd_rn(r[j], __fmul_rn(p[i + j], p[i + j]));
  }
  return __fadd_rn(__fadd_rn(__fadd_rn(r[0], r[1]), __fadd_rn(r[2], r[3])),
                   __fadd_rn(__fadd_rn(r[4], r[5]), __fadd_rn(r[6], r[7])));
}

// ---------- kernel 3: wave-per-row candidate filter + exact fp32 rescore ----------
__global__ __launch_bounds__(256) void k_pick(const int2* __restrict__ part2,
                                              const float* __restrict__ zf,
                                              const float* __restrict__ ew,
                                              float* __restrict__ idxF,
                                              float* __restrict__ losspart,
                                              int* __restrict__ ghist) {
  __shared__ int cand[4][40];
  __shared__ int cnts[4];
  const int t = threadIdx.x, lane = t & 63, wv = t >> 6;
  const int row = blockIdx.x * 4 + wv;
  if (lane == 0) cnts[wv] = 0;
  int2 pv;
  if (lane < 16) pv = part2[row * 16 + lane];
  else { pv.x = 0x7fffffff; pv.y = 0x7fffffff; }
  int kmin = pv.x;
#pragma unroll
  for (int d = 1; d < 64; d <<= 1) kmin = min(kmin, __shfl_xor(kmin, d));
  const int qthr = min((kmin >> 13) + QMARGIN, 262143);
  const int kthr = (qthr << 13) | 8191;
  __syncthreads();
  if (lane < 16) {
    if (pv.x <= kthr) { int p = atomicAdd(&cnts[wv], 1); cand[wv][p] = pv.x & 8191; }
    if (pv.y <= kthr) { int p = atomicAdd(&cnts[wv], 1); cand[wv][p] = pv.y & 8191; }
  }
  __syncthreads();
  const int cnt = cnts[wv];
  const float* zr = zf + (size_t)row * DIM;
  float bd = INFINITY; int bj = 0x7fffffff;
  if (lane < cnt) {
    int j = cand[wv][lane];
    const float* e = ew + (size_t)j * DIM;
    float acc = 0.f;
    for (int k = 0; k < DIM; k += 4) {   // float4 loads, same sequential fma order
      float4 e4 = *(const float4*)(e + k);
      float4 z4 = *(const float4*)(zr + k);
      acc = __builtin_fmaf(z4.x, e4.x, acc);
      acc = __builtin_fmaf(z4.y, e4.y, acc);
      acc = __builtin_fmaf(z4.z, e4.z, acc);
      acc = __builtin_fmaf(z4.w, e4.w, acc);
    }
    float esq = __fadd_rn(np_sumsq_128(e), np_sumsq_128(e + 128));
    float zsq = __fadd_rn(np_sumsq_128(zr), np_sumsq_128(zr + 128));
    bd = __fsub_rn(__fadd_rn(zsq, esq), __fmul_rn(2.0f, acc));
    bj = j;
  }
#pragma unroll
  for (int d = 1; d < 64; d <<= 1) {
    float od = __shfl_xor(bd, d); int oj = __shfl_xor(bj, d);
    if (od < bd || (od == bd && oj < bj)) { bd = od; bj = oj; }
  }
  // loss partial
  int c = lane * 4;
  float4 e4 = *reinterpret_cast<const float4*>(ew + (size_t)bj * DIM + c);
  float4 z4 = *reinterpret_cast<const float4*>(zr + c);
  float t0 = __fsub_rn(e4.x, z4.x), t1 = __fsub_rn(e4.y, z4.y);
  float t2 = __fsub_rn(e4.z, z4.z), t3 = __fsub_rn(e4.w, z4.w);
  float s = __fadd_rn(__fadd_rn(__fmul_rn(t0, t0), __fmul_rn(t1, t1)),
                      __fadd_rn(__fmul_rn(t2, t2), __fmul_rn(t3, t3)));
#pragma unroll
  for (int d = 1; d < 64; d <<= 1) s += __shfl_xor(s, d);
  if (lane == 0) {
    idxF[row] = (float)bj;
    losspart[row] = s;
    atomicAdd(&ghist[bj], 1);   // device-scope histogram, replaces k_scalars pass
  }
}

// ---------- kernel 4: loss + perplexity (reads prebuilt ghist) ----------
__global__ __launch_bounds__(256) void k_scalars(const int* __restrict__ ghist,
                                                 const float* __restrict__ losspart,
                                                 float* __restrict__ out) {
  __shared__ float red[256];
  int t = threadIdx.x;
  float ls = 0.f;
  for (int i = t; i < N_ROWS; i += 256) ls += losspart[i];
  float es = 0.f;
  for (int i = t; i < NE; i += 256) {
    float p = (float)ghist[i] * (1.0f / 16384.0f);
    es += p * logf(p + 1e-10f);
  }
  red[t] = es; __syncthreads();
  for (int w = 128; w > 0; w >>= 1) { if (t < w) red[t] += red[t + w]; __syncthreads(); }
  float esum = red[0]; __syncthreads();
  red[t] = ls; __syncthreads();
  for (int w = 128; w > 0; w >>= 1) { if (t < w) red[t] += red[t + w]; __syncthreads(); }
  if (t == 0) {
    out[4194305] = expf(-esum);
    float m = red[0] * (1.0f / 4194304.0f);
    out[0] = __fadd_rn(m, __fmul_rn(0.25f, m));
  }
}

// ---------- kernel 5 (LAST): z_q_st + one_hot finish ----------
__global__ void k_zq_out(const float* __restrict__ z, const float* __restrict__ ew,
                         const float* __restrict__ idxF, float* __restrict__ out) {
  __shared__ float tileE[32][33];
  __shared__ int sidx[32];
  int ct = blockIdx.x, ht = blockIdx.y, b = blockIdx.z;
  int tx = threadIdx.x & 31, ty = threadIdx.x >> 5;
  int c0 = ct * 32, hw0 = ht * 32;
  if (threadIdx.x < 32) sidx[threadIdx.x] = (int)idxF[b * 1024 + hw0 + threadIdx.x];
  __syncthreads();
#pragma unroll
  for (int p = 0; p < 4; ++p) {
    int r = p * 8 + ty;
    tileE[tx][r] = ew[(size_t)sidx[r] * DIM + c0 + tx];
  }
  __syncthreads();
  float* outq = out + 1;
#pragma unroll
  for (int p = 0; p < 4; ++p) {
    int cl = p * 8 + ty;
    size_t gi = (size_t)(b * 256 + c0 + cl) * 1024 + hw0 + tx;
    float zv = z[gi];
    outq[gi] = __fadd_rn(zv, __fsub_rn(tileE[cl][tx], zv));
  }

  // ---- fused one_hot finish (all scratch dead by now) ----
  const int fid = blockIdx.x + 8 * blockIdx.y + 256 * blockIdx.z;  // 0..4095
  float* oh = out + 4194306;
  // (a) idx-aware zero/ones of rows 0..962, float4 region rel [2, 7888894)
  {
    f32x4* dst4 = (f32x4*)(out + 4194308);
#pragma unroll
    for (int p = 0; p < 2; ++p) {
      int slot = p * 256 + (int)threadIdx.x;
      size_t g4 = (size_t)fid * ZQ4_PER_BLK + slot;
      if (slot < ZQ4_PER_BLK && g4 < ZQ4_COUNT) {
        size_t rel = g4 * 4 + 2;
        int ra = (int)(rel >> 13), rb = (int)((rel + 3) >> 13);
        int ia = (int)idxF[ra];
        int ib = (ra == rb) ? ia : (int)idxF[rb];
        f32x4 v;
#pragma unroll
        for (int j = 0; j < 4; ++j) {
          size_t rj = rel + j;
          int rowj = (int)(rj >> 13), colj = (int)(rj & 8191);
          int idxj = (rowj == ra) ? ia : ib;
          v[j] = (colj == idxj) ? 1.f : 0.f;
        }
        __builtin_nontemporal_store(v, dst4 + g4);
      }
    }
  }
  // (b) scattered ones for rows >= 963 (bulk pre-zeroed by k_score)
  if (threadIdx.x < 4) {
    int r = fid * 4 + (int)threadIdx.x;
    if (r >= 963 && r < N_ROWS) {
      int idx = (int)idxF[r];
      oh[(size_t)r * NE + idx] = 1.0f;
    }
  }
  // (c) boundary words: row0 cols0/1, row962 cols 8190/8191,
  //     row963 cols0/1 (ghist tail restore), row16383 cols 8190/8191
  if (fid == 0 && threadIdx.x == 4) {
    int i0 = (int)idxF[0];
    oh[0] = (i0 == 0) ? 1.f : 0.f;
    oh[1] = (i0 == 1) ? 1.f : 0.f;
    int i962 = (int)idxF[962];
    oh[(size_t)962 * NE + 8190] = (i962 == 8190) ? 1.f : 0.f;
    oh[(size_t)962 * NE + 8191] = (i962 == 8191) ? 1.f : 0.f;
    int i963 = (int)idxF[963];
    oh[(size_t)963 * NE + 0] = (i963 == 0) ? 1.f : 0.f;
    oh[(size_t)963 * NE + 1] = (i963 == 1) ? 1.f : 0.f;
    int il = (int)idxF[16383];
    oh[(size_t)16383 * NE + 8190] = (il == 8190) ? 1.f : 0.f;
    oh[(size_t)16383 * NE + 8191] = (il == 8191) ? 1.f : 0.f;
  }
}

extern "C" void kernel_launch(void* const* d_in, const int* in_sizes, int n_in,
                              void* d_out, int out_size, void* d_ws, size_t ws_size,
                              hipStream_t stream) {
  const float* z  = (const float*)d_in[0];
  const float* ew = (const float*)d_in[1];
  float* out = (float*)d_out;
  float*  zf    = out + SOFF;
  __bf16* zfb   = (__bf16*)(out + SOFF + 4194304);
  __bf16* ewb   = (__bf16*)(out + SOFF + 6291456);
  int2*   part2 = (int2*)(out + SOFF + 7340032);
  float*  lprt  = out + SOFF + 7864320;
  int*    ghist = (int*)(out + GHOFF);
  float*  idxF  = out + 138412034;

  k_prep<<<dim3(8, 32, 16), 256, 0, stream>>>(z, ew, zf, zfb, ewb, ghist);
  k_score<<<dim3(128, 8), 256, 0, stream>>>(zfb, ewb, part2, out);
  k_pick<<<dim3(4096), 256, 0, stream>>>(part2, zf, ew, idxF, lprt, ghist);
  k_scalars<<<1, 256, 0, stream>>>(ghist, lprt, out);
  k_zq_out<<<dim3(8, 32, 16), 256, 0, stream>>>(z, ew, idxF, out);
}